// Round 6
// baseline (233.430 us; speedup 1.0000x reference)
//
#include <hip/hip_runtime.h>
#include <hip/hip_bf16.h>

// B=512, I=1152, K=8, L=16, O=7; IK=9216, LO=112.
// MFMA routing, bf16 inputs / fp32 accumulate, 11 dispatches total:
//   prep0: x->xbf,xT (bf16) + wcT0 = bf16(w/1152)           (fused, once)
//   s_gemm: part[kc] = xbf . wcT (MFMA, 96-way K-split, no LDS)
//   squash: reduce partials, squash, write vT bf16 (+out fp32 last iter)
//   g_fused: G = xT.vT (MFMA, 2-way B-split) -> in-reg w-contraction -> bij halves
//   smaxwc: softmax(bij0+bij1) fused with wcT build
// Iter 3's bij update is dead code -> skipped. No atomics, no memsets.

#define NB 512
#define NI 1152
#define NLO 112
#define NIK 9216
#define KSPLIT 96            // 96 chunks of 96 k (3 MFMA k-steps)
#define SPART 57344          // 512*112

typedef __attribute__((ext_vector_type(8))) short bf16x8;
typedef __attribute__((ext_vector_type(4))) float f32x4;

__device__ __forceinline__ ushort f2bf(float f) {
    __hip_bfloat16 h = __float2bfloat16(f);
    return *(ushort*)&h;
}

// ---- body: softmax over i of (bij0+bij1) fused with wcT tile build ----
__device__ __forceinline__ void smaxwc_body(const float* __restrict__ bij0,
                                            const float* __restrict__ bij1,
                                            const float* __restrict__ w,
                                            ushort* __restrict__ wcT,
                                            int ik0, int it0flag) {
    __shared__ ushort tile[NLO][66];
    __shared__ float cs[128];        // [i_local*16 + l], 8 i's per block
    __shared__ float red[256];
    __shared__ float m_l[16], inv_l[16];
    int t = threadIdx.x;
    if (!it0flag) {
        // stride 256 == 0 mod 16 -> thread t always sees l = t&15
        float mx = -1e30f;
        for (int e = t; e < NI * 16; e += 256) mx = fmaxf(mx, bij0[e] + bij1[e]);
        red[t] = mx; __syncthreads();
        if (t < 16) {
            float m = red[t];
            #pragma unroll
            for (int j = 1; j < 16; ++j) m = fmaxf(m, red[t + j * 16]);
            m_l[t] = m;
        }
        __syncthreads();
        float m = m_l[t & 15];
        float sm = 0.f;
        for (int e = t; e < NI * 16; e += 256) sm += expf(bij0[e] + bij1[e] - m);
        red[t] = sm; __syncthreads();
        if (t < 16) {
            float s = 0.f;
            #pragma unroll
            for (int j = 0; j < 16; ++j) s += red[t + j * 16];
            inv_l[t] = 1.0f / s;
        }
        __syncthreads();
        if (t < 128) {
            int i = (ik0 >> 3) + (t >> 4), l = t & 15;
            cs[t] = expf(bij0[i * 16 + l] + bij1[i * 16 + l] - m_l[l]) * inv_l[l];
        }
    } else {
        if (t < 128) cs[t] = 1.0f / 1152.0f;
    }
    __syncthreads();
    for (int e = t; e < 7168; e += 256) {
        int ikl = e / NLO, lo = e - ikl * NLO;
        int il = ((ikl >> 3) << 4) + lo / 7;       // i_local*16 + l
        tile[lo][ikl] = f2bf(cs[il] * w[(size_t)(ik0 + ikl) * NLO + lo]);
    }
    __syncthreads();
    for (int e = t; e < 7168; e += 256) {
        int lo = e >> 6, ikl = e & 63;
        wcT[(size_t)lo * NIK + ik0 + ikl] = tile[lo][ikl];
    }
}

// ---- conv_x body: x fp32 -> xbf [b][ik] and xT [ik][b], both bf16 ----
__device__ __forceinline__ void conv_x_body(const float* __restrict__ x,
                                            ushort* __restrict__ xbf,
                                            ushort* __restrict__ xT, int bid) {
    __shared__ ushort tile[64][68];
    int kg = bid % 144, bg = bid / 144;
    int k0 = kg * 64, b0 = bg * 64;
    int t = threadIdx.x;
    for (int e = t; e < 1024; e += 256) {
        int r = e >> 4, c4 = (e & 15) * 4;
        float4 f = *(const float4*)&x[(size_t)(b0 + r) * NIK + k0 + c4];
        ushort4 u = { f2bf(f.x), f2bf(f.y), f2bf(f.z), f2bf(f.w) };
        *(ushort4*)&xbf[(size_t)(b0 + r) * NIK + k0 + c4] = u;
        tile[r][c4] = u.x; tile[r][c4 + 1] = u.y; tile[r][c4 + 2] = u.z; tile[r][c4 + 3] = u.w;
    }
    __syncthreads();
    for (int e = t; e < 1024; e += 256) {
        int kr = e >> 4, c4 = (e & 15) * 4;
        ushort4 u = { tile[c4][kr], tile[c4 + 1][kr], tile[c4 + 2][kr], tile[c4 + 3][kr] };
        *(ushort4*)&xT[(size_t)(k0 + kr) * NB + b0 + c4] = u;
    }
}

// ---- prep0: conv_x (blocks 0..1151) + iter0 wcT = w/1152 (blocks 1152..1295) ----
__global__ __launch_bounds__(256) void prep0(const float* __restrict__ x,
                                             ushort* __restrict__ xbf,
                                             ushort* __restrict__ xT,
                                             const float* __restrict__ w,
                                             ushort* __restrict__ wcT) {
    if (blockIdx.x < 1152) conv_x_body(x, xbf, xT, blockIdx.x);
    else smaxwc_body(nullptr, nullptr, w, wcT, (blockIdx.x - 1152) * 64, 1);
}

// ---- standalone smaxwc for iters 1,2 ----
__global__ __launch_bounds__(256) void smaxwc(const float* __restrict__ bijp,
                                              const float* __restrict__ w,
                                              ushort* __restrict__ wcT) {
    smaxwc_body(bijp, bijp + NI * 16, w, wcT, blockIdx.x * 64, 0);
}

// ---- s_gemm: pure-MFMA, no LDS. wave = 16b M-tile x 7 N-tiles x 96k chunk ----
__global__ __launch_bounds__(256) void s_gemm(const ushort* __restrict__ xbf,
                                              const ushort* __restrict__ wcT,
                                              float* __restrict__ part) {
    int wid = blockIdx.x * 4 + (threadIdx.x >> 6);   // 768 blocks -> 3072 waves
    int lane = threadIdx.x & 63;
    int mt = wid & 31;               // 32 M-tiles of 16 batches
    int kc = wid >> 5;               // 96 K-chunks of 96
    int b0 = mt * 16, k0 = kc * 96;
    int row = lane & 15, quad = lane >> 4;
    const ushort* ap = xbf + (size_t)(b0 + row) * NIK + k0 + quad * 8;
    const ushort* bp = wcT + (size_t)row * NIK + k0 + quad * 8;   // + nt*16*NIK
    f32x4 acc[7];
    #pragma unroll
    for (int nt = 0; nt < 7; ++nt) acc[nt] = (f32x4){0.f, 0.f, 0.f, 0.f};
    #pragma unroll
    for (int ks = 0; ks < 3; ++ks) {                 // 96/32 k-steps
        bf16x8 a = *(const bf16x8*)(ap + ks * 32);
        #pragma unroll
        for (int nt = 0; nt < 7; ++nt) {
            bf16x8 bfr = *(const bf16x8*)(bp + (size_t)nt * 16 * NIK + ks * 32);
            acc[nt] = __builtin_amdgcn_mfma_f32_16x16x32_bf16(a, bfr, acc[nt], 0, 0, 0);
        }
    }
    float* pp = part + (size_t)kc * SPART + (size_t)(b0 + quad * 4) * NLO + row;
    #pragma unroll
    for (int nt = 0; nt < 7; ++nt)
        #pragma unroll
        for (int r = 0; r < 4; ++r)
            pp[(size_t)r * NLO + nt * 16] = acc[nt][r];
}

// ---- fused K-split reduce + squash; 2 batches per block ----
__global__ __launch_bounds__(256) void squash_k(const float* __restrict__ part,
                                                ushort* __restrict__ vT,
                                                float* __restrict__ out, int write_out) {
    int half = threadIdx.x >> 7;
    int b = blockIdx.x * 2 + half;   // 256 blocks
    int t = threadIdx.x & 127;
    __shared__ float sh[2][NLO];
    __shared__ float fac[2][16];
    float sv = 0.f;
    if (t < NLO) {
        const float* p = part + (size_t)b * NLO + t;
        #pragma unroll 8
        for (int kc = 0; kc < KSPLIT; ++kc) sv += p[(size_t)kc * SPART];
        sh[half][t] = sv;
    }
    __syncthreads();
    if (t < 16) {
        float sq = 0.f;
        #pragma unroll
        for (int o = 0; o < 7; ++o) { float e = sh[half][t * 7 + o]; sq += e * e; }
        fac[half][t] = sqrtf(sq) / (1.0f + sq);   // == (sq/(1+sq))/norm
    }
    __syncthreads();
    if (t < NLO) {
        int l = t / 7, o = t - l * 7;
        float vv = sv * fac[half][l];
        vT[(size_t)(o * 16 + l) * NB + b] = f2bf(vv);
        if (write_out) out[(size_t)b * NLO + o * 16 + l] = vv;
    }
}

// ---- g_fused: MFMA G-tile over half of B (256), in-register w contraction ----
// Exclusive (half,i,l) ownership -> plain stores; it0 store / it>0 accumulate.
__global__ __launch_bounds__(256) void g_fused(const ushort* __restrict__ xT,
                                               const ushort* __restrict__ vT,
                                               const float* __restrict__ w,
                                               float* __restrict__ bijp, int accum) {
    int wid = blockIdx.x * 4 + (threadIdx.x >> 6);   // 288 blocks -> 1152 waves
    int lane = threadIdx.x & 63;
    int half = wid & 1;
    int m0 = (wid >> 1) * 16;                        // ik tile base
    int kb0 = half * 256;
    int row = lane & 15, quad = lane >> 4;
    const ushort* ap = xT + (size_t)(m0 + row) * NB + kb0 + quad * 8;
    const ushort* bp = vT + (size_t)row * NB + kb0 + quad * 8;    // + nt*16*NB
    f32x4 acc[7];
    #pragma unroll
    for (int nt = 0; nt < 7; ++nt) acc[nt] = (f32x4){0.f, 0.f, 0.f, 0.f};
    for (int ks = 0; ks < 8; ++ks) {                 // 256/32
        bf16x8 a = *(const bf16x8*)(ap + ks * 32);
        #pragma unroll
        for (int nt = 0; nt < 7; ++nt) {
            bf16x8 bfr = *(const bf16x8*)(bp + (size_t)nt * 16 * NB + ks * 32);
            acc[nt] = __builtin_amdgcn_mfma_f32_16x16x32_bf16(a, bfr, acc[nt], 0, 0, 0);
        }
    }
    // lane holds G[ik = m0+quad*4+r][o*16+l], o = nt, l = row
    float S = 0.f;
    #pragma unroll
    for (int r = 0; r < 4; ++r) {
        int ik = m0 + quad * 4 + r;
        const float* wr = w + (size_t)ik * NLO + row * 7;
        float p = 0.f;
        #pragma unroll
        for (int o = 0; o < 7; ++o) p += wr[o] * acc[o][r];
        S += p;
    }
    float Sp = __shfl_down(S, 16);                   // partner quad's 4-ik sum
    if ((quad & 1) == 0) {
        int i = (m0 >> 3) + (quad >> 1);             // wave owns i, i+1 within its half
        float val = (S + Sp) * (1.0f / 512.0f);
        float* dst = bijp + (size_t)half * (NI * 16) + i * 16 + row;
        *dst = accum ? (*dst + val) : val;
    }
}

extern "C" void kernel_launch(void* const* d_in, const int* in_sizes, int n_in,
                              void* d_out, int out_size, void* d_ws, size_t ws_size,
                              hipStream_t stream) {
    const float* x = (const float*)d_in[0];   // [512][9216]
    const float* w = (const float*)d_in[1];   // [9216][112]
    float* out = (float*)d_out;               // [512][112]
    float* ws = (float*)d_ws;
    float*  f_bijp = ws;                                  // 2*18432
    float*  f_part = f_bijp + 2 * NI * 16;                // 96*57344
    ushort* xbf    = (ushort*)(f_part + (size_t)KSPLIT * SPART);  // 512*9216
    ushort* xT     = xbf + (size_t)NB * NIK;              // 9216*512
    ushort* wcT    = xT + (size_t)NIK * NB;               // 112*9216
    ushort* vT     = wcT + (size_t)NLO * NIK;             // 112*512
    prep0<<<1296, 256, 0, stream>>>(x, xbf, xT, w, wcT);
    for (int it = 0; it < 3; ++it) {
        if (it > 0) smaxwc<<<144, 256, 0, stream>>>(f_bijp, w, wcT);
        s_gemm<<<768, 256, 0, stream>>>(xbf, wcT, f_part);
        squash_k<<<256, 256, 0, stream>>>(f_part, vT, out, it == 2 ? 1 : 0);
        if (it < 2) g_fused<<<288, 256, 0, stream>>>(xT, vT, w, f_bijp, it);
    }
}